// Round 9
// baseline (287.483 us; speedup 1.0000x reference)
//
#include <hip/hip_runtime.h>
#include <hip/hip_fp16.h>
#include <math.h>

#define N_NODES 100000
#define N_EDGES 3200000
#define EPRIME  (N_EDGES + N_NODES)
#define NFEAT   512
#define HID     16
#define NCLS    10

#define NPB     256                            // nodes per bucket
#define NB      ((N_NODES + NPB - 1) / NPB)    // 391 buckets
#define CHUNK   4096                           // edges per partition chunk
#define NCH     ((EPRIME + CHUNK - 1) / CHUNK) // 806 chunks
#define CAPB    10240                          // fixed csr region per bucket (mean 8448 + ~20 sigma)

union U2 { unsigned int u; __half2 h; };
__device__ __forceinline__ float2 u2f(unsigned int v) {
  U2 t; t.u = v; return __half22float2(t.h);
}

// ---------------------------------------------------------------------------
// D1: partition each 4096-edge chunk into its OWN slot region, grouped by
// bucket, plus packed header hdr[c*NB+b] = (start<<16)|cnt.  Pure overwrite:
// no global atomics, no initialization required.
// ---------------------------------------------------------------------------
__global__ __launch_bounds__(256) void k_part2(const int* __restrict__ ei,
                                               unsigned int* __restrict__ slots,
                                               unsigned int* __restrict__ hdr) {
  __shared__ int sh_hist[NB];
  __shared__ int sh_start[NB];
  const int c = blockIdx.x, tid = threadIdx.x;

  for (int i = tid; i < NB; i += 256) sh_hist[i] = 0;
  __syncthreads();

  const int base = c * CHUNK;
  unsigned int pk[16];
  int bk[16], rk[16];
#pragma unroll
  for (int j = 0; j < 16; ++j) {
    int e = base + j * 256 + tid;
    bool valid = (e < EPRIME);
    int srcv = 0, d = 0;
    if (valid) {
      if (e < N_EDGES) { srcv = ei[e]; d = ei[N_EDGES + e]; }
      else             { srcv = d = e - N_EDGES; }
    }
    bk[j] = valid ? (d >> 8) : -1;
    pk[j] = (unsigned)srcv | ((unsigned)(d & 255) << 20);
    rk[j] = valid ? atomicAdd(&sh_hist[d >> 8], 1) : 0;
  }
  __syncthreads();

  // wave 0: exclusive scan of sh_hist[0..NB) into sh_start
  if (tid < 64) {
    int carry = 0;
    for (int b0 = 0; b0 < NB; b0 += 64) {
      const int idx = b0 + tid;
      const int v = (idx < NB) ? sh_hist[idx] : 0;
      int s = v;
#pragma unroll
      for (int d = 1; d < 64; d <<= 1) {
        int u = __shfl_up(s, d);
        if (tid >= d) s += u;
      }
      if (idx < NB) sh_start[idx] = s - v + carry;
      carry += __shfl(s, 63);
    }
  }
  __syncthreads();

  // coalesced header write (c-major)
  for (int b = tid; b < NB; b += 256)
    hdr[(size_t)c * NB + b] = ((unsigned)sh_start[b] << 16) | (unsigned)sh_hist[b];

  // scatter into this chunk's 16KB slot region (L2-local)
#pragma unroll
  for (int j = 0; j < 16; ++j)
    if (bk[j] >= 0)
      slots[(size_t)base + sh_start[bk[j]] + rk[j]] = pk[j];
}

// ---------------------------------------------------------------------------
// D3: per-bucket CSR finalize into fixed region [b*CAPB, b*CAPB+ne).
// Two passes over this bucket's runs in the chunk-local slots (via headers).
// Writes soffs[node] (global start) and ecnt[node] (count); zeroes the 16
// entries past ne (pull over-read pad — the gap to CAPB is 0xAA poison).
// ---------------------------------------------------------------------------
__global__ __launch_bounds__(256) void k_csrfin(const unsigned int* __restrict__ slots,
                                                const unsigned int* __restrict__ hdr,
                                                unsigned int* __restrict__ csr,
                                                unsigned int* __restrict__ soffs,
                                                unsigned short* __restrict__ ecnt) {
  __shared__ int sh_cnt[NPB];
  __shared__ int sh_cnt2[NPB];
  __shared__ int sh_sc[NPB];
  __shared__ int sh_loffs[NPB];
  const int b = blockIdx.x, tid = threadIdx.x;

  sh_cnt[tid] = 0;
  sh_cnt2[tid] = 0;
  __syncthreads();

  // pass 1: per-local-node histogram
  for (int c = tid; c < NCH; c += 256) {
    const unsigned h = hdr[(size_t)c * NB + b];
    const int cnt = h & 0xFFFF, st = h >> 16;
    const unsigned int* p = slots + (size_t)c * CHUNK + st;
    for (int i = 0; i < cnt; ++i) atomicAdd(&sh_cnt[p[i] >> 20], 1);
  }
  __syncthreads();

  const int v = sh_cnt[tid];
  sh_sc[tid] = v;
  __syncthreads();
  for (int d = 1; d < NPB; d <<= 1) {
    int u = (tid >= d) ? sh_sc[tid - d] : 0;
    __syncthreads();
    sh_sc[tid] += u;
    __syncthreads();
  }
  const int excl = sh_sc[tid] - v;
  sh_loffs[tid] = excl;

  const int ne = sh_sc[NPB - 1];  // bucket total (max ~8.8k << CAPB-16)
  if (tid < 16) csr[(size_t)b * CAPB + ne + tid] = 0;  // over-read pad

  const int node = b * NPB + tid;
  if (node < N_NODES) {
    soffs[node] = (unsigned)(b * CAPB + excl);
    ecnt[node]  = (unsigned short)v;
  }
  __syncthreads();

  // pass 2: scatter srcs into the bucket's csr region (~40KB, L2-local)
  for (int c = tid; c < NCH; c += 256) {
    const unsigned h = hdr[(size_t)c * NB + b];
    const int cnt = h & 0xFFFF, st = h >> 16;
    const unsigned int* p = slots + (size_t)c * CHUNK + st;
    for (int i = 0; i < cnt; ++i) {
      const unsigned pv = p[i];
      const int local = pv >> 20;
      const int r = atomicAdd(&sh_cnt2[local], 1);
      csr[(size_t)b * CAPB + sh_loffs[local] + r] = pv & 0xFFFFF;
    }
  }
}

// ---------------------------------------------------------------------------
// D2: hn1 = fp16(normalize(relu(x @ W1 + b1))); norms1 = ||relu||.
// One wave per row; W1 (512x16) in registers; prefetch depth 2.
// STANDALONE (round-8 fusion capped it at 92 VGPR -> weight spill).
// ---------------------------------------------------------------------------
__global__ __launch_bounds__(256) void k_gemm_norm(const float* __restrict__ x,
                                                   const float* __restrict__ W1,
                                                   const float* __restrict__ b1,
                                                   __half* __restrict__ hn1,
                                                   float* __restrict__ norms1) {
  const int lane = threadIdx.x & 63;
  const int wid  = blockIdx.x * 4 + (threadIdx.x >> 6);
  const int nw   = gridDim.x * 4;

  float4 w[8][4];
#pragma unroll
  for (int kk = 0; kk < 8; ++kk)
#pragma unroll
    for (int j = 0; j < 4; ++j)
      w[kk][j] = *reinterpret_cast<const float4*>(W1 + (lane * 8 + kk) * 16 + j * 4);

  const int outCol = (lane >> 2) & 15;
  const float bias = b1[outCol];

  const float4 z4 = make_float4(0.f, 0.f, 0.f, 0.f);
  float4 c0 = z4, c1 = z4, p0 = z4, p1 = z4, t0 = z4, t1 = z4;

  if (wid < N_NODES) {
    c0 = *reinterpret_cast<const float4*>(x + (size_t)wid * NFEAT + lane * 8);
    c1 = *reinterpret_cast<const float4*>(x + (size_t)wid * NFEAT + lane * 8 + 4);
  }
  if (wid + nw < N_NODES) {
    p0 = *reinterpret_cast<const float4*>(x + (size_t)(wid + nw) * NFEAT + lane * 8);
    p1 = *reinterpret_cast<const float4*>(x + (size_t)(wid + nw) * NFEAT + lane * 8 + 4);
  }

  for (int row = wid; row < N_NODES; row += nw) {
    const int r2 = row + 2 * nw;
    if (r2 < N_NODES) {
      t0 = *reinterpret_cast<const float4*>(x + (size_t)r2 * NFEAT + lane * 8);
      t1 = *reinterpret_cast<const float4*>(x + (size_t)r2 * NFEAT + lane * 8 + 4);
    }

    float xs[8] = {c0.x, c0.y, c0.z, c0.w, c1.x, c1.y, c1.z, c1.w};

    float acc[16];
#pragma unroll
    for (int j = 0; j < 16; ++j) acc[j] = 0.f;

#pragma unroll
    for (int kk = 0; kk < 8; ++kk) {
      const float xv = xs[kk];
#pragma unroll
      for (int j4 = 0; j4 < 4; ++j4) {
        acc[j4 * 4 + 0] = fmaf(xv, w[kk][j4].x, acc[j4 * 4 + 0]);
        acc[j4 * 4 + 1] = fmaf(xv, w[kk][j4].y, acc[j4 * 4 + 1]);
        acc[j4 * 4 + 2] = fmaf(xv, w[kk][j4].z, acc[j4 * 4 + 2]);
        acc[j4 * 4 + 3] = fmaf(xv, w[kk][j4].w, acc[j4 * 4 + 3]);
      }
    }

#pragma unroll
    for (int i = 0; i < 8; ++i) {
      float send = (lane & 32) ? acc[i] : acc[i + 8];
      float r = __shfl_xor(send, 32);
      acc[i] = ((lane & 32) ? acc[i + 8] : acc[i]) + r;
    }
#pragma unroll
    for (int i = 0; i < 4; ++i) {
      float send = (lane & 16) ? acc[i] : acc[i + 4];
      float r = __shfl_xor(send, 16);
      acc[i] = ((lane & 16) ? acc[i + 4] : acc[i]) + r;
    }
#pragma unroll
    for (int i = 0; i < 2; ++i) {
      float send = (lane & 8) ? acc[i] : acc[i + 2];
      float r = __shfl_xor(send, 8);
      acc[i] = ((lane & 8) ? acc[i + 2] : acc[i]) + r;
    }
    {
      float send = (lane & 4) ? acc[0] : acc[1];
      float r = __shfl_xor(send, 4);
      acc[0] = ((lane & 4) ? acc[1] : acc[0]) + r;
    }
    acc[0] += __shfl_xor(acc[0], 2);
    acc[0] += __shfl_xor(acc[0], 1);

    const float v = fmaxf(acc[0] + bias, 0.f);
    float ss = v * v;
    ss += __shfl_xor(ss, 4);
    ss += __shfl_xor(ss, 8);
    ss += __shfl_xor(ss, 16);
    ss += __shfl_xor(ss, 32);
    const float nrm = sqrtf(ss);
    const float vs = v / fmaxf(nrm, 1e-12f);

    const float wv = __shfl(vs, (lane & 15) * 4);
    if (lane < 16) hn1[(size_t)row * HID + lane] = __float2half_rn(wv);
    if (lane == 0) norms1[row] = nrm;

    c0 = p0; c1 = p1; p0 = t0; p1 = t1;
  }
}

// ---------------------------------------------------------------------------
// Pull-mode AGNN conv, one wave per dst node.  16 edge slots x 4 feature
// lanes; hn fp16 (L2-resident), fp32 accumulate.  FINAL=false: fuse next
// layer's normalize.  FINAL=true: fuse logits + log_softmax.
// Over-read past e (up to 15 slots) reads the zeroed pad -> src=0, t=0.
// ---------------------------------------------------------------------------
template <bool FINAL>
__device__ __forceinline__ void pull_body(const __half* __restrict__ hn,
                                          const float* __restrict__ norms,
                                          const unsigned int* __restrict__ soffs,
                                          const unsigned short* __restrict__ ecnt,
                                          const unsigned int* __restrict__ csr,
                                          float beta,
                                          __half* __restrict__ out_hn,
                                          float* __restrict__ out_norms,
                                          const float* __restrict__ W2,
                                          const float* __restrict__ b2,
                                          float* __restrict__ out) {
  const int node = blockIdx.x * 4 + (threadIdx.x >> 6);
  if (node >= N_NODES) return;
  const int lane = threadIdx.x & 63;
  const int q    = lane & 3;   // feature quad
  const int slot = lane >> 2;  // edge slot 0..15

  float w4x = 0.f, w4y = 0.f, w4z = 0.f, w4w = 0.f, b2v = 0.f;
  if (FINAL) {
    const int sc = (slot < NCLS) ? slot : 0;
    w4x = W2[(q * 4 + 0) * NCLS + sc];
    w4y = W2[(q * 4 + 1) * NCLS + sc];
    w4z = W2[(q * 4 + 2) * NCLS + sc];
    w4w = W2[(q * 4 + 3) * NCLS + sc];
    b2v = b2[sc];
  }

  const uint2 qraw = *reinterpret_cast<const uint2*>(hn + (size_t)node * HID + q * 4);
  const float2 qa = u2f(qraw.x), qb = u2f(qraw.y);
  const unsigned s = soffs[node];
  const unsigned e = s + ecnt[node];

  float den = 0.f;
  float ax = 0.f, ay = 0.f, az = 0.f, aw = 0.f;

  for (unsigned bi = s; bi < e; bi += 16) {
    const unsigned i = bi + slot;
    const int src = (int)csr[i];  // past-e reads hit the zero pad
    const uint2 r = *reinterpret_cast<const uint2*>(hn + (size_t)src * HID + q * 4);
    const float2 f0 = u2f(r.x), f1 = u2f(r.y);
    float pd = qa.x * f0.x + qa.y * f0.y + qb.x * f1.x + qb.y * f1.y;
    pd += __shfl_xor(pd, 1);
    pd += __shfl_xor(pd, 2);
    const float t = (i < e) ? __expf(beta * pd) : 0.f;
    den += t;
    const float wgt = t * norms[src];
    ax += wgt * f0.x; ay += wgt * f0.y; az += wgt * f1.x; aw += wgt * f1.y;
  }

#pragma unroll
  for (int m = 4; m <= 32; m <<= 1) {
    den += __shfl_xor(den, m);
    ax  += __shfl_xor(ax, m);
    ay  += __shfl_xor(ay, m);
    az  += __shfl_xor(az, m);
    aw  += __shfl_xor(aw, m);
  }
  const float inv = 1.0f / den;  // self-loop guarantees den > 0
  ax *= inv; ay *= inv; az *= inv; aw *= inv;

  if (!FINAL) {
    float ssn = ax * ax + ay * ay + az * az + aw * aw;
    ssn += __shfl_xor(ssn, 1);
    ssn += __shfl_xor(ssn, 2);
    const float nrm = sqrtf(ssn);
    const float ninv = 1.0f / fmaxf(nrm, 1e-12f);
    if (lane < 4) {
      U2 lo, hi;
      lo.h = __floats2half2_rn(ax * ninv, ay * ninv);
      hi.h = __floats2half2_rn(az * ninv, aw * ninv);
      *reinterpret_cast<uint2*>(out_hn + (size_t)node * HID + q * 4) =
          make_uint2(lo.u, hi.u);
      if (lane == 0) out_norms[node] = nrm;
    }
  } else {
    float part = ax * w4x + ay * w4y + az * w4z + aw * w4w;
    part += __shfl_xor(part, 1);
    part += __shfl_xor(part, 2);
    const float logit = part + b2v;  // valid on slots 0..9 (all q replicate)

    float lg[NCLS];
#pragma unroll
    for (int c = 0; c < NCLS; ++c) lg[c] = __shfl(logit, c * 4);
    float m = lg[0];
#pragma unroll
    for (int c = 1; c < NCLS; ++c) m = fmaxf(m, lg[c]);
    float se = 0.f;
#pragma unroll
    for (int c = 0; c < NCLS; ++c) se += __expf(lg[c] - m);
    const float ls = m + logf(se);

    const float myv = __shfl(logit, lane * 4);
    if (lane < NCLS) out[(size_t)node * NCLS + lane] = myv - ls;
  }
}

__global__ __launch_bounds__(256) void k_pull1(const __half* __restrict__ hn1,
                                               const float* __restrict__ norms1,
                                               const unsigned int* __restrict__ soffs,
                                               const unsigned short* __restrict__ ecnt,
                                               const unsigned int* __restrict__ csr,
                                               __half* __restrict__ hn2,
                                               float* __restrict__ norms2) {
  pull_body<false>(hn1, norms1, soffs, ecnt, csr, 1.0f, hn2, norms2,
                   nullptr, nullptr, nullptr);
}

__global__ __launch_bounds__(256) void k_pull2(const __half* __restrict__ hn2,
                                               const float* __restrict__ norms2,
                                               const unsigned int* __restrict__ soffs,
                                               const unsigned short* __restrict__ ecnt,
                                               const unsigned int* __restrict__ csr,
                                               const float* __restrict__ beta_ptr,
                                               const float* __restrict__ W2,
                                               const float* __restrict__ b2,
                                               float* __restrict__ out) {
  pull_body<true>(hn2, norms2, soffs, ecnt, csr, beta_ptr[0], nullptr, nullptr,
                  W2, b2, out);
}

// ---------------------------------------------------------------------------
extern "C" void kernel_launch(void* const* d_in, const int* in_sizes, int n_in,
                              void* d_out, int out_size, void* d_ws, size_t ws_size,
                              hipStream_t stream) {
  const float* x    = (const float*)d_in[0];
  const int*   ei   = (const int*)d_in[1];
  const float* W1   = (const float*)d_in[2];
  const float* b1   = (const float*)d_in[3];
  const float* beta = (const float*)d_in[4];
  const float* W2   = (const float*)d_in[5];
  const float* b2   = (const float*)d_in[6];
  float* out = (float*)d_out;

  // Workspace layout (~39 MB); every array 16B-aligned by construction.
  char* p = (char*)d_ws;
  __half* hn1 = (__half*)p;                 p += (size_t)N_NODES * HID * 2;
  float* norms1 = (float*)p;                p += (size_t)N_NODES * 4;
  __half* hn2 = (__half*)p;                 p += (size_t)N_NODES * HID * 2;
  float* norms2 = (float*)p;                p += (size_t)N_NODES * 4;
  unsigned int* soffs = (unsigned int*)p;   p += (size_t)N_NODES * 4;
  unsigned short* ecnt = (unsigned short*)p; p += (size_t)N_NODES * 2 + 64;
  unsigned int* csr = (unsigned int*)p;     p += ((size_t)NB * CAPB + 16) * 4;
  unsigned int* slots = (unsigned int*)p;   p += (size_t)NCH * CHUNK * 4;
  unsigned int* hdr = (unsigned int*)p;     // NCH*NB u32

  k_part2<<<NCH, 256, 0, stream>>>(ei, slots, hdr);
  k_gemm_norm<<<1024, 256, 0, stream>>>(x, W1, b1, hn1, norms1);
  k_csrfin<<<NB, 256, 0, stream>>>(slots, hdr, csr, soffs, ecnt);

  const int nblW = (N_NODES + 3) / 4;  // wave per node, 4 waves/block
  k_pull1<<<nblW, 256, 0, stream>>>(hn1, norms1, soffs, ecnt, csr, hn2, norms2);
  k_pull2<<<nblW, 256, 0, stream>>>(hn2, norms2, soffs, ecnt, csr, beta, W2, b2, out);
}

// Round 10
// 260.021 us; speedup vs baseline: 1.1056x; 1.1056x over previous
//
#include <hip/hip_runtime.h>
#include <hip/hip_fp16.h>
#include <math.h>

#define N_NODES 100000
#define N_EDGES 3200000
#define EPRIME  (N_EDGES + N_NODES)
#define NFEAT   512
#define HID     16
#define NCLS    10

#define NPB     256                            // nodes per bucket
#define NB      ((N_NODES + NPB - 1) / NPB)    // 391 buckets
#define CHUNK   4096                           // edges per partition chunk
#define NCH     ((EPRIME + CHUNK - 1) / CHUNK) // 806 chunks
#define CAPB    10240                          // fixed region per bucket (mean 8448 + ~19 sigma)

union U2 { unsigned int u; __half2 h; };
__device__ __forceinline__ float2 u2f(unsigned int v) {
  U2 t; t.u = v; return __half22float2(t.h);
}

// ---------------------------------------------------------------------------
// D1: hn1 = fp16(normalize(relu(x @ W1 + b1))); norms1 = ||relu||.
// One wave per row; W1 (512x16) in registers; prefetch depth 2.
// Standalone (round-8: fusing anything in caps VGPR at 92 -> weight spill).
// Block 0 zeroes gcur for the next dispatch.
// ---------------------------------------------------------------------------
__global__ __launch_bounds__(256) void k_gemm_norm(const float* __restrict__ x,
                                                   const float* __restrict__ W1,
                                                   const float* __restrict__ b1,
                                                   __half* __restrict__ hn1,
                                                   float* __restrict__ norms1,
                                                   int* __restrict__ gcur) {
  if (blockIdx.x == 0)
    for (int i = threadIdx.x; i < NB; i += 256) gcur[i] = 0;

  const int lane = threadIdx.x & 63;
  const int wid  = blockIdx.x * 4 + (threadIdx.x >> 6);
  const int nw   = gridDim.x * 4;

  float4 w[8][4];
#pragma unroll
  for (int kk = 0; kk < 8; ++kk)
#pragma unroll
    for (int j = 0; j < 4; ++j)
      w[kk][j] = *reinterpret_cast<const float4*>(W1 + (lane * 8 + kk) * 16 + j * 4);

  const int outCol = (lane >> 2) & 15;
  const float bias = b1[outCol];

  const float4 z4 = make_float4(0.f, 0.f, 0.f, 0.f);
  float4 c0 = z4, c1 = z4, p0 = z4, p1 = z4, t0 = z4, t1 = z4;

  if (wid < N_NODES) {
    c0 = *reinterpret_cast<const float4*>(x + (size_t)wid * NFEAT + lane * 8);
    c1 = *reinterpret_cast<const float4*>(x + (size_t)wid * NFEAT + lane * 8 + 4);
  }
  if (wid + nw < N_NODES) {
    p0 = *reinterpret_cast<const float4*>(x + (size_t)(wid + nw) * NFEAT + lane * 8);
    p1 = *reinterpret_cast<const float4*>(x + (size_t)(wid + nw) * NFEAT + lane * 8 + 4);
  }

  for (int row = wid; row < N_NODES; row += nw) {
    const int r2 = row + 2 * nw;
    if (r2 < N_NODES) {
      t0 = *reinterpret_cast<const float4*>(x + (size_t)r2 * NFEAT + lane * 8);
      t1 = *reinterpret_cast<const float4*>(x + (size_t)r2 * NFEAT + lane * 8 + 4);
    }

    float xs[8] = {c0.x, c0.y, c0.z, c0.w, c1.x, c1.y, c1.z, c1.w};

    float acc[16];
#pragma unroll
    for (int j = 0; j < 16; ++j) acc[j] = 0.f;

#pragma unroll
    for (int kk = 0; kk < 8; ++kk) {
      const float xv = xs[kk];
#pragma unroll
      for (int j4 = 0; j4 < 4; ++j4) {
        acc[j4 * 4 + 0] = fmaf(xv, w[kk][j4].x, acc[j4 * 4 + 0]);
        acc[j4 * 4 + 1] = fmaf(xv, w[kk][j4].y, acc[j4 * 4 + 1]);
        acc[j4 * 4 + 2] = fmaf(xv, w[kk][j4].z, acc[j4 * 4 + 2]);
        acc[j4 * 4 + 3] = fmaf(xv, w[kk][j4].w, acc[j4 * 4 + 3]);
      }
    }

#pragma unroll
    for (int i = 0; i < 8; ++i) {
      float send = (lane & 32) ? acc[i] : acc[i + 8];
      float r = __shfl_xor(send, 32);
      acc[i] = ((lane & 32) ? acc[i + 8] : acc[i]) + r;
    }
#pragma unroll
    for (int i = 0; i < 4; ++i) {
      float send = (lane & 16) ? acc[i] : acc[i + 4];
      float r = __shfl_xor(send, 16);
      acc[i] = ((lane & 16) ? acc[i + 4] : acc[i]) + r;
    }
#pragma unroll
    for (int i = 0; i < 2; ++i) {
      float send = (lane & 8) ? acc[i] : acc[i + 2];
      float r = __shfl_xor(send, 8);
      acc[i] = ((lane & 8) ? acc[i + 2] : acc[i]) + r;
    }
    {
      float send = (lane & 4) ? acc[0] : acc[1];
      float r = __shfl_xor(send, 4);
      acc[0] = ((lane & 4) ? acc[1] : acc[0]) + r;
    }
    acc[0] += __shfl_xor(acc[0], 2);
    acc[0] += __shfl_xor(acc[0], 1);

    const float v = fmaxf(acc[0] + bias, 0.f);
    float ss = v * v;
    ss += __shfl_xor(ss, 4);
    ss += __shfl_xor(ss, 8);
    ss += __shfl_xor(ss, 16);
    ss += __shfl_xor(ss, 32);
    const float nrm = sqrtf(ss);
    const float vs = v / fmaxf(nrm, 1e-12f);

    const float wv = __shfl(vs, (lane & 15) * 4);
    if (lane < 16) hn1[(size_t)row * HID + lane] = __float2half_rn(wv);
    if (lane == 0) norms1[row] = nrm;

    c0 = p0; c1 = p1; p0 = t0; p1 = t1;
  }
}

// ---------------------------------------------------------------------------
// D2: partition edges into per-bucket slot regions of packed u32
// (src | local_dst<<20).  One 4096-edge chunk per block; LDS histogram
// gives per-edge rank; one global atomic per touched bucket reserves a
// contiguous run in slots[b*CAPB ...].  (Round-4 proven structure.)
// ---------------------------------------------------------------------------
__global__ __launch_bounds__(256) void k_part(const int* __restrict__ ei,
                                              int* __restrict__ gcur,
                                              unsigned int* __restrict__ slots) {
  __shared__ int sh_hist[NB];
  __shared__ int sh_gbase[NB];
  const int tid = threadIdx.x;

  for (int i = tid; i < NB; i += 256) sh_hist[i] = 0;
  __syncthreads();

  const int base = blockIdx.x * CHUNK;
  unsigned int pk[16];
  int bk[16], rk[16];
#pragma unroll
  for (int j = 0; j < 16; ++j) {
    int e = base + j * 256 + tid;
    bool valid = (e < EPRIME);
    int srcv = 0, d = 0;
    if (valid) {
      if (e < N_EDGES) { srcv = ei[e]; d = ei[N_EDGES + e]; }
      else             { srcv = d = e - N_EDGES; }
    }
    bk[j] = valid ? (d >> 8) : -1;
    pk[j] = (unsigned)srcv | ((unsigned)(d & 255) << 20);
    rk[j] = valid ? atomicAdd(&sh_hist[d >> 8], 1) : 0;
  }
  __syncthreads();

  for (int i = tid; i < NB; i += 256) {
    int hc = sh_hist[i];
    sh_gbase[i] = hc ? atomicAdd(&gcur[i], hc) : 0;
  }
  __syncthreads();

#pragma unroll
  for (int j = 0; j < 16; ++j)
    if (bk[j] >= 0)
      slots[(size_t)bk[j] * CAPB + sh_gbase[bk[j]] + rk[j]] = pk[j];
}

// ---------------------------------------------------------------------------
// D3: per-bucket CSR finalize.  Reads its slot region with COALESCED
// strided loads (i = tid; i += 256), LDS histogram -> scan -> direct
// scatter into the fixed csr region [b*CAPB, b*CAPB+ne) (L2-local 40KB).
// Writes soffs/ecnt; zeroes the 16-entry over-read pad past ne.
// ---------------------------------------------------------------------------
__global__ __launch_bounds__(256) void k_csr(const unsigned int* __restrict__ slots,
                                             const int* __restrict__ gcur,
                                             unsigned int* __restrict__ csr,
                                             unsigned int* __restrict__ soffs,
                                             unsigned short* __restrict__ ecnt) {
  __shared__ int sh_cnt[NPB];
  __shared__ int sh_cnt2[NPB];
  __shared__ int sh_sc[NPB];
  __shared__ int sh_loffs[NPB];
  const int b = blockIdx.x, tid = threadIdx.x;
  const int ne = gcur[b];
  const unsigned int* my = slots + (size_t)b * CAPB;

  sh_cnt[tid] = 0;
  sh_cnt2[tid] = 0;
  __syncthreads();

  for (int i = tid; i < ne; i += 256) atomicAdd(&sh_cnt[my[i] >> 20], 1);
  __syncthreads();

  const int v = sh_cnt[tid];
  sh_sc[tid] = v;
  __syncthreads();
  for (int d = 1; d < NPB; d <<= 1) {
    int u = (tid >= d) ? sh_sc[tid - d] : 0;
    __syncthreads();
    sh_sc[tid] += u;
    __syncthreads();
  }
  const int excl = sh_sc[tid] - v;
  sh_loffs[tid] = excl;

  if (tid < 16) csr[(size_t)b * CAPB + ne + tid] = 0;  // over-read pad

  const int node = b * NPB + tid;
  if (node < N_NODES) {
    soffs[node] = (unsigned)(b * CAPB + excl);
    ecnt[node]  = (unsigned short)v;
  }
  __syncthreads();

  for (int i = tid; i < ne; i += 256) {
    const unsigned pv = my[i];
    const int local = pv >> 20;
    const int r = atomicAdd(&sh_cnt2[local], 1);
    csr[(size_t)b * CAPB + sh_loffs[local] + r] = pv & 0xFFFFF;
  }
}

// ---------------------------------------------------------------------------
// Pull-mode AGNN conv, one wave per dst node.  16 edge slots x 4 feature
// lanes; hn fp16 (L2-resident), fp32 accumulate.  FINAL=false: fuse next
// layer's normalize.  FINAL=true: fuse logits + log_softmax.
// Over-read past e (up to 15 slots) reads the zeroed pad -> src=0, t=0.
// ---------------------------------------------------------------------------
template <bool FINAL>
__device__ __forceinline__ void pull_body(const __half* __restrict__ hn,
                                          const float* __restrict__ norms,
                                          const unsigned int* __restrict__ soffs,
                                          const unsigned short* __restrict__ ecnt,
                                          const unsigned int* __restrict__ csr,
                                          float beta,
                                          __half* __restrict__ out_hn,
                                          float* __restrict__ out_norms,
                                          const float* __restrict__ W2,
                                          const float* __restrict__ b2,
                                          float* __restrict__ out) {
  const int node = blockIdx.x * 4 + (threadIdx.x >> 6);
  if (node >= N_NODES) return;
  const int lane = threadIdx.x & 63;
  const int q    = lane & 3;   // feature quad
  const int slot = lane >> 2;  // edge slot 0..15

  float w4x = 0.f, w4y = 0.f, w4z = 0.f, w4w = 0.f, b2v = 0.f;
  if (FINAL) {
    const int sc = (slot < NCLS) ? slot : 0;
    w4x = W2[(q * 4 + 0) * NCLS + sc];
    w4y = W2[(q * 4 + 1) * NCLS + sc];
    w4z = W2[(q * 4 + 2) * NCLS + sc];
    w4w = W2[(q * 4 + 3) * NCLS + sc];
    b2v = b2[sc];
  }

  const uint2 qraw = *reinterpret_cast<const uint2*>(hn + (size_t)node * HID + q * 4);
  const float2 qa = u2f(qraw.x), qb = u2f(qraw.y);
  const unsigned s = soffs[node];
  const unsigned e = s + ecnt[node];

  float den = 0.f;
  float ax = 0.f, ay = 0.f, az = 0.f, aw = 0.f;

  for (unsigned bi = s; bi < e; bi += 16) {
    const unsigned i = bi + slot;
    const int src = (int)csr[i];  // past-e reads hit the zero pad
    const uint2 r = *reinterpret_cast<const uint2*>(hn + (size_t)src * HID + q * 4);
    const float2 f0 = u2f(r.x), f1 = u2f(r.y);
    float pd = qa.x * f0.x + qa.y * f0.y + qb.x * f1.x + qb.y * f1.y;
    pd += __shfl_xor(pd, 1);
    pd += __shfl_xor(pd, 2);
    const float t = (i < e) ? __expf(beta * pd) : 0.f;
    den += t;
    const float wgt = t * norms[src];
    ax += wgt * f0.x; ay += wgt * f0.y; az += wgt * f1.x; aw += wgt * f1.y;
  }

#pragma unroll
  for (int m = 4; m <= 32; m <<= 1) {
    den += __shfl_xor(den, m);
    ax  += __shfl_xor(ax, m);
    ay  += __shfl_xor(ay, m);
    az  += __shfl_xor(az, m);
    aw  += __shfl_xor(aw, m);
  }
  const float inv = 1.0f / den;  // self-loop guarantees den > 0
  ax *= inv; ay *= inv; az *= inv; aw *= inv;

  if (!FINAL) {
    float ssn = ax * ax + ay * ay + az * az + aw * aw;
    ssn += __shfl_xor(ssn, 1);
    ssn += __shfl_xor(ssn, 2);
    const float nrm = sqrtf(ssn);
    const float ninv = 1.0f / fmaxf(nrm, 1e-12f);
    if (lane < 4) {
      U2 lo, hi;
      lo.h = __floats2half2_rn(ax * ninv, ay * ninv);
      hi.h = __floats2half2_rn(az * ninv, aw * ninv);
      *reinterpret_cast<uint2*>(out_hn + (size_t)node * HID + q * 4) =
          make_uint2(lo.u, hi.u);
      if (lane == 0) out_norms[node] = nrm;
    }
  } else {
    float part = ax * w4x + ay * w4y + az * w4z + aw * w4w;
    part += __shfl_xor(part, 1);
    part += __shfl_xor(part, 2);
    const float logit = part + b2v;  // valid on slots 0..9 (all q replicate)

    float lg[NCLS];
#pragma unroll
    for (int c = 0; c < NCLS; ++c) lg[c] = __shfl(logit, c * 4);
    float m = lg[0];
#pragma unroll
    for (int c = 1; c < NCLS; ++c) m = fmaxf(m, lg[c]);
    float se = 0.f;
#pragma unroll
    for (int c = 0; c < NCLS; ++c) se += __expf(lg[c] - m);
    const float ls = m + logf(se);

    const float myv = __shfl(logit, lane * 4);
    if (lane < NCLS) out[(size_t)node * NCLS + lane] = myv - ls;
  }
}

__global__ __launch_bounds__(256) void k_pull1(const __half* __restrict__ hn1,
                                               const float* __restrict__ norms1,
                                               const unsigned int* __restrict__ soffs,
                                               const unsigned short* __restrict__ ecnt,
                                               const unsigned int* __restrict__ csr,
                                               __half* __restrict__ hn2,
                                               float* __restrict__ norms2) {
  pull_body<false>(hn1, norms1, soffs, ecnt, csr, 1.0f, hn2, norms2,
                   nullptr, nullptr, nullptr);
}

__global__ __launch_bounds__(256) void k_pull2(const __half* __restrict__ hn2,
                                               const float* __restrict__ norms2,
                                               const unsigned int* __restrict__ soffs,
                                               const unsigned short* __restrict__ ecnt,
                                               const unsigned int* __restrict__ csr,
                                               const float* __restrict__ beta_ptr,
                                               const float* __restrict__ W2,
                                               const float* __restrict__ b2,
                                               float* __restrict__ out) {
  pull_body<true>(hn2, norms2, soffs, ecnt, csr, beta_ptr[0], nullptr, nullptr,
                  W2, b2, out);
}

// ---------------------------------------------------------------------------
extern "C" void kernel_launch(void* const* d_in, const int* in_sizes, int n_in,
                              void* d_out, int out_size, void* d_ws, size_t ws_size,
                              hipStream_t stream) {
  const float* x    = (const float*)d_in[0];
  const int*   ei   = (const int*)d_in[1];
  const float* W1   = (const float*)d_in[2];
  const float* b1   = (const float*)d_in[3];
  const float* beta = (const float*)d_in[4];
  const float* W2   = (const float*)d_in[5];
  const float* b2   = (const float*)d_in[6];
  float* out = (float*)d_out;

  // Workspace layout (~39 MB); every array 16B-aligned by construction.
  char* p = (char*)d_ws;
  __half* hn1 = (__half*)p;                 p += (size_t)N_NODES * HID * 2;
  float* norms1 = (float*)p;                p += (size_t)N_NODES * 4;
  __half* hn2 = (__half*)p;                 p += (size_t)N_NODES * HID * 2;
  float* norms2 = (float*)p;                p += (size_t)N_NODES * 4;
  unsigned int* soffs = (unsigned int*)p;   p += (size_t)N_NODES * 4;
  unsigned short* ecnt = (unsigned short*)p; p += (size_t)N_NODES * 2 + 64;
  int* gcur = (int*)p;                      p += (size_t)NB * 4 + 32;
  unsigned int* csr = (unsigned int*)p;     p += ((size_t)NB * CAPB + 16) * 4;
  unsigned int* slots = (unsigned int*)p;   // NB*CAPB u32

  k_gemm_norm<<<1024, 256, 0, stream>>>(x, W1, b1, hn1, norms1, gcur);
  k_part<<<NCH, 256, 0, stream>>>(ei, gcur, slots);
  k_csr<<<NB, 256, 0, stream>>>(slots, gcur, csr, soffs, ecnt);

  const int nblW = (N_NODES + 3) / 4;  // wave per node, 4 waves/block
  k_pull1<<<nblW, 256, 0, stream>>>(hn1, norms1, soffs, ecnt, csr, hn2, norms2);
  k_pull2<<<nblW, 256, 0, stream>>>(hn2, norms2, soffs, ecnt, csr, beta, W2, b2, out);
}

// Round 11
// 259.953 us; speedup vs baseline: 1.1059x; 1.0003x over previous
//
#include <hip/hip_runtime.h>
#include <hip/hip_fp16.h>
#include <math.h>

#define N_NODES 100000
#define N_EDGES 3200000
#define EPRIME  (N_EDGES + N_NODES)
#define NFEAT   512
#define HID     16
#define NCLS    10

#define NPB     256                            // nodes per bucket
#define NB      ((N_NODES + NPB - 1) / NPB)    // 391 buckets
#define CHUNK   4096                           // edges per partition chunk
#define NCH     ((EPRIME + CHUNK - 1) / CHUNK) // 806 chunks
#define CAPB    10240                          // fixed region per bucket (mean 8448 + ~19 sigma)
#define GBLK    2048                           // gemm blocks (2 rows each)

union U2 { unsigned int u; __half2 h; };
__device__ __forceinline__ float2 u2f(unsigned int v) {
  U2 t; t.u = v; return __half22float2(t.h);
}

// ---------------------------------------------------------------------------
// D1: hn1 = fp16(normalize(relu(x @ W1 + b1))); norms1 = ||relu||.
// SPLIT-K: 4 waves/block = 2 rows x 2 K-halves.  Each wave holds only
// half of W1 (64 VGPR) -> ~120 VGPR total -> 4 waves/SIMD (2x the old
// occupancy; old monolithic version measured ~140us, 3.5x its HBM floor).
// Cross-half combine via 512B double-buffered LDS + 1 barrier/row.
// Block 0 zeroes gcur for the next dispatch.
// ---------------------------------------------------------------------------
__global__ __launch_bounds__(256, 4) void k_gemm_norm(const float* __restrict__ x,
                                                      const float* __restrict__ W1,
                                                      const float* __restrict__ b1,
                                                      __half* __restrict__ hn1,
                                                      float* __restrict__ norms1,
                                                      int* __restrict__ gcur) {
  if (blockIdx.x == 0)
    for (int i = threadIdx.x; i < NB; i += 256) gcur[i] = 0;

  __shared__ float red[2][2][2][16];  // [parity][rowInBlk][half][col]

  const int lane = threadIdx.x & 63;
  const int wv   = threadIdx.x >> 6;  // 0..3
  const int r    = wv >> 1;           // row in block
  const int h    = wv & 1;            // K-half
  const int stride = GBLK * 2;
  const int row0 = blockIdx.x * 2 + r;
  const int nIter = (N_NODES - 1 - blockIdx.x * 2) / stride + 1;  // block-uniform

  // W1 fragment: k = h*256 + lane*4 + kk  (4 k-slices x 16 cols = 64 VGPR)
  float4 w[4][4];
#pragma unroll
  for (int kk = 0; kk < 4; ++kk)
#pragma unroll
    for (int j = 0; j < 4; ++j)
      w[kk][j] = *reinterpret_cast<const float4*>(
          W1 + (size_t)(h * 256 + lane * 4 + kk) * 16 + j * 4);

  const float bias = (lane < 16) ? b1[lane] : 0.f;
  const int koff = h * 256 + lane * 4;

  const float4 z4 = make_float4(0.f, 0.f, 0.f, 0.f);
  float4 c0 = z4, p0 = z4, t0 = z4;

  if (row0 < N_NODES)
    c0 = *reinterpret_cast<const float4*>(x + (size_t)row0 * NFEAT + koff);
  if (row0 + stride < N_NODES)
    p0 = *reinterpret_cast<const float4*>(x + (size_t)(row0 + stride) * NFEAT + koff);

  for (int i = 0; i < nIter; ++i) {
    const int row = row0 + i * stride;
    const int r2 = row + 2 * stride;
    if (r2 < N_NODES)
      t0 = *reinterpret_cast<const float4*>(x + (size_t)r2 * NFEAT + koff);

    const float xs[4] = {c0.x, c0.y, c0.z, c0.w};

    float acc[16];
#pragma unroll
    for (int j = 0; j < 16; ++j) acc[j] = 0.f;

#pragma unroll
    for (int kk = 0; kk < 4; ++kk) {
      const float xv = xs[kk];
#pragma unroll
      for (int j4 = 0; j4 < 4; ++j4) {
        acc[j4 * 4 + 0] = fmaf(xv, w[kk][j4].x, acc[j4 * 4 + 0]);
        acc[j4 * 4 + 1] = fmaf(xv, w[kk][j4].y, acc[j4 * 4 + 1]);
        acc[j4 * 4 + 2] = fmaf(xv, w[kk][j4].z, acc[j4 * 4 + 2]);
        acc[j4 * 4 + 3] = fmaf(xv, w[kk][j4].w, acc[j4 * 4 + 3]);
      }
    }

    // intra-wave halving butterfly: lane ends holding this K-half's full
    // column sum for col (lane>>2)&15 (quad-uniform).
#pragma unroll
    for (int j = 0; j < 8; ++j) {
      float send = (lane & 32) ? acc[j] : acc[j + 8];
      float rr = __shfl_xor(send, 32);
      acc[j] = ((lane & 32) ? acc[j + 8] : acc[j]) + rr;
    }
#pragma unroll
    for (int j = 0; j < 4; ++j) {
      float send = (lane & 16) ? acc[j] : acc[j + 4];
      float rr = __shfl_xor(send, 16);
      acc[j] = ((lane & 16) ? acc[j + 4] : acc[j]) + rr;
    }
#pragma unroll
    for (int j = 0; j < 2; ++j) {
      float send = (lane & 8) ? acc[j] : acc[j + 2];
      float rr = __shfl_xor(send, 8);
      acc[j] = ((lane & 8) ? acc[j + 2] : acc[j]) + rr;
    }
    {
      float send = (lane & 4) ? acc[0] : acc[1];
      float rr = __shfl_xor(send, 4);
      acc[0] = ((lane & 4) ? acc[1] : acc[0]) + rr;
    }
    acc[0] += __shfl_xor(acc[0], 2);
    acc[0] += __shfl_xor(acc[0], 1);

    if ((lane & 3) == 0) red[i & 1][r][h][lane >> 2] = acc[0];
    __syncthreads();

    if (h == 0 && row < N_NODES) {
      float v = 0.f;
      if (lane < 16)
        v = fmaxf(red[i & 1][r][0][lane] + red[i & 1][r][1][lane] + bias, 0.f);
      float ss = v * v;
      ss += __shfl_xor(ss, 1);
      ss += __shfl_xor(ss, 2);
      ss += __shfl_xor(ss, 4);
      ss += __shfl_xor(ss, 8);
      const float nrm = sqrtf(ss);
      const float inv = 1.0f / fmaxf(nrm, 1e-12f);
      if (lane < 16) hn1[(size_t)row * HID + lane] = __float2half_rn(v * inv);
      if (lane == 0) norms1[row] = nrm;
    }

    c0 = p0; p0 = t0;
  }
}

// ---------------------------------------------------------------------------
// D2: partition edges into per-bucket slot regions of packed u32
// (src | local_dst<<20).  One 4096-edge chunk per block; LDS histogram
// gives per-edge rank; one global atomic per touched bucket reserves a
// contiguous run in slots[b*CAPB ...].
// ---------------------------------------------------------------------------
__global__ __launch_bounds__(256) void k_part(const int* __restrict__ ei,
                                              int* __restrict__ gcur,
                                              unsigned int* __restrict__ slots) {
  __shared__ int sh_hist[NB];
  __shared__ int sh_gbase[NB];
  const int tid = threadIdx.x;

  for (int i = tid; i < NB; i += 256) sh_hist[i] = 0;
  __syncthreads();

  const int base = blockIdx.x * CHUNK;
  unsigned int pk[16];
  int bk[16], rk[16];
#pragma unroll
  for (int j = 0; j < 16; ++j) {
    int e = base + j * 256 + tid;
    bool valid = (e < EPRIME);
    int srcv = 0, d = 0;
    if (valid) {
      if (e < N_EDGES) { srcv = ei[e]; d = ei[N_EDGES + e]; }
      else             { srcv = d = e - N_EDGES; }
    }
    bk[j] = valid ? (d >> 8) : -1;
    pk[j] = (unsigned)srcv | ((unsigned)(d & 255) << 20);
    rk[j] = valid ? atomicAdd(&sh_hist[d >> 8], 1) : 0;
  }
  __syncthreads();

  for (int i = tid; i < NB; i += 256) {
    int hc = sh_hist[i];
    sh_gbase[i] = hc ? atomicAdd(&gcur[i], hc) : 0;
  }
  __syncthreads();

#pragma unroll
  for (int j = 0; j < 16; ++j)
    if (bk[j] >= 0)
      slots[(size_t)bk[j] * CAPB + sh_gbase[bk[j]] + rk[j]] = pk[j];
}

// ---------------------------------------------------------------------------
// D3: per-bucket CSR finalize.  Coalesced strided reads of the slot
// region, LDS histogram -> scan -> direct scatter into the fixed csr
// region [b*CAPB, b*CAPB+ne) (L2-local).  Writes soffs/ecnt; zeroes the
// 16-entry over-read pad past ne.
// ---------------------------------------------------------------------------
__global__ __launch_bounds__(256) void k_csr(const unsigned int* __restrict__ slots,
                                             const int* __restrict__ gcur,
                                             unsigned int* __restrict__ csr,
                                             unsigned int* __restrict__ soffs,
                                             unsigned short* __restrict__ ecnt) {
  __shared__ int sh_cnt[NPB];
  __shared__ int sh_cnt2[NPB];
  __shared__ int sh_sc[NPB];
  __shared__ int sh_loffs[NPB];
  const int b = blockIdx.x, tid = threadIdx.x;
  const int ne = gcur[b];
  const unsigned int* my = slots + (size_t)b * CAPB;

  sh_cnt[tid] = 0;
  sh_cnt2[tid] = 0;
  __syncthreads();

  for (int i = tid; i < ne; i += 256) atomicAdd(&sh_cnt[my[i] >> 20], 1);
  __syncthreads();

  const int v = sh_cnt[tid];
  sh_sc[tid] = v;
  __syncthreads();
  for (int d = 1; d < NPB; d <<= 1) {
    int u = (tid >= d) ? sh_sc[tid - d] : 0;
    __syncthreads();
    sh_sc[tid] += u;
    __syncthreads();
  }
  const int excl = sh_sc[tid] - v;
  sh_loffs[tid] = excl;

  if (tid < 16) csr[(size_t)b * CAPB + ne + tid] = 0;  // over-read pad

  const int node = b * NPB + tid;
  if (node < N_NODES) {
    soffs[node] = (unsigned)(b * CAPB + excl);
    ecnt[node]  = (unsigned short)v;
  }
  __syncthreads();

  for (int i = tid; i < ne; i += 256) {
    const unsigned pv = my[i];
    const int local = pv >> 20;
    const int rr = atomicAdd(&sh_cnt2[local], 1);
    csr[(size_t)b * CAPB + sh_loffs[local] + rr] = pv & 0xFFFFF;
  }
}

// ---------------------------------------------------------------------------
// Pull-mode AGNN conv, one wave per dst node.  16 edge slots x 4 feature
// lanes; hn fp16 (L2-resident), fp32 accumulate.  FINAL=false: fuse next
// layer's normalize.  FINAL=true: fuse logits + log_softmax.
// Over-read past e (up to 15 slots) reads the zeroed pad -> src=0, t=0.
// ---------------------------------------------------------------------------
template <bool FINAL>
__device__ __forceinline__ void pull_body(const __half* __restrict__ hn,
                                          const float* __restrict__ norms,
                                          const unsigned int* __restrict__ soffs,
                                          const unsigned short* __restrict__ ecnt,
                                          const unsigned int* __restrict__ csr,
                                          float beta,
                                          __half* __restrict__ out_hn,
                                          float* __restrict__ out_norms,
                                          const float* __restrict__ W2,
                                          const float* __restrict__ b2,
                                          float* __restrict__ out) {
  const int node = blockIdx.x * 4 + (threadIdx.x >> 6);
  if (node >= N_NODES) return;
  const int lane = threadIdx.x & 63;
  const int q    = lane & 3;   // feature quad
  const int slot = lane >> 2;  // edge slot 0..15

  float w4x = 0.f, w4y = 0.f, w4z = 0.f, w4w = 0.f, b2v = 0.f;
  if (FINAL) {
    const int sc = (slot < NCLS) ? slot : 0;
    w4x = W2[(q * 4 + 0) * NCLS + sc];
    w4y = W2[(q * 4 + 1) * NCLS + sc];
    w4z = W2[(q * 4 + 2) * NCLS + sc];
    w4w = W2[(q * 4 + 3) * NCLS + sc];
    b2v = b2[sc];
  }

  const uint2 qraw = *reinterpret_cast<const uint2*>(hn + (size_t)node * HID + q * 4);
  const float2 qa = u2f(qraw.x), qb = u2f(qraw.y);
  const unsigned s = soffs[node];
  const unsigned e = s + ecnt[node];

  float den = 0.f;
  float ax = 0.f, ay = 0.f, az = 0.f, aw = 0.f;

  for (unsigned bi = s; bi < e; bi += 16) {
    const unsigned i = bi + slot;
    const int src = (int)csr[i];  // past-e reads hit the zero pad
    const uint2 rr = *reinterpret_cast<const uint2*>(hn + (size_t)src * HID + q * 4);
    const float2 f0 = u2f(rr.x), f1 = u2f(rr.y);
    float pd = qa.x * f0.x + qa.y * f0.y + qb.x * f1.x + qb.y * f1.y;
    pd += __shfl_xor(pd, 1);
    pd += __shfl_xor(pd, 2);
    const float t = (i < e) ? __expf(beta * pd) : 0.f;
    den += t;
    const float wgt = t * norms[src];
    ax += wgt * f0.x; ay += wgt * f0.y; az += wgt * f1.x; aw += wgt * f1.y;
  }

#pragma unroll
  for (int m = 4; m <= 32; m <<= 1) {
    den += __shfl_xor(den, m);
    ax  += __shfl_xor(ax, m);
    ay  += __shfl_xor(ay, m);
    az  += __shfl_xor(az, m);
    aw  += __shfl_xor(aw, m);
  }
  const float inv = 1.0f / den;  // self-loop guarantees den > 0
  ax *= inv; ay *= inv; az *= inv; aw *= inv;

  if (!FINAL) {
    float ssn = ax * ax + ay * ay + az * az + aw * aw;
    ssn += __shfl_xor(ssn, 1);
    ssn += __shfl_xor(ssn, 2);
    const float nrm = sqrtf(ssn);
    const float ninv = 1.0f / fmaxf(nrm, 1e-12f);
    if (lane < 4) {
      U2 lo, hi;
      lo.h = __floats2half2_rn(ax * ninv, ay * ninv);
      hi.h = __floats2half2_rn(az * ninv, aw * ninv);
      *reinterpret_cast<uint2*>(out_hn + (size_t)node * HID + q * 4) =
          make_uint2(lo.u, hi.u);
      if (lane == 0) out_norms[node] = nrm;
    }
  } else {
    float part = ax * w4x + ay * w4y + az * w4z + aw * w4w;
    part += __shfl_xor(part, 1);
    part += __shfl_xor(part, 2);
    const float logit = part + b2v;  // valid on slots 0..9 (all q replicate)

    float lg[NCLS];
#pragma unroll
    for (int c = 0; c < NCLS; ++c) lg[c] = __shfl(logit, c * 4);
    float m = lg[0];
#pragma unroll
    for (int c = 1; c < NCLS; ++c) m = fmaxf(m, lg[c]);
    float se = 0.f;
#pragma unroll
    for (int c = 0; c < NCLS; ++c) se += __expf(lg[c] - m);
    const float ls = m + logf(se);

    const float myv = __shfl(logit, lane * 4);
    if (lane < NCLS) out[(size_t)node * NCLS + lane] = myv - ls;
  }
}

__global__ __launch_bounds__(256) void k_pull1(const __half* __restrict__ hn1,
                                               const float* __restrict__ norms1,
                                               const unsigned int* __restrict__ soffs,
                                               const unsigned short* __restrict__ ecnt,
                                               const unsigned int* __restrict__ csr,
                                               __half* __restrict__ hn2,
                                               float* __restrict__ norms2) {
  pull_body<false>(hn1, norms1, soffs, ecnt, csr, 1.0f, hn2, norms2,
                   nullptr, nullptr, nullptr);
}

__global__ __launch_bounds__(256) void k_pull2(const __half* __restrict__ hn2,
                                               const float* __restrict__ norms2,
                                               const unsigned int* __restrict__ soffs,
                                               const unsigned short* __restrict__ ecnt,
                                               const unsigned int* __restrict__ csr,
                                               const float* __restrict__ beta_ptr,
                                               const float* __restrict__ W2,
                                               const float* __restrict__ b2,
                                               float* __restrict__ out) {
  pull_body<true>(hn2, norms2, soffs, ecnt, csr, beta_ptr[0], nullptr, nullptr,
                  W2, b2, out);
}

// ---------------------------------------------------------------------------
extern "C" void kernel_launch(void* const* d_in, const int* in_sizes, int n_in,
                              void* d_out, int out_size, void* d_ws, size_t ws_size,
                              hipStream_t stream) {
  const float* x    = (const float*)d_in[0];
  const int*   ei   = (const int*)d_in[1];
  const float* W1   = (const float*)d_in[2];
  const float* b1   = (const float*)d_in[3];
  const float* beta = (const float*)d_in[4];
  const float* W2   = (const float*)d_in[5];
  const float* b2   = (const float*)d_in[6];
  float* out = (float*)d_out;

  // Workspace layout (~39 MB); every array 16B-aligned by construction.
  char* p = (char*)d_ws;
  __half* hn1 = (__half*)p;                 p += (size_t)N_NODES * HID * 2;
  float* norms1 = (float*)p;                p += (size_t)N_NODES * 4;
  __half* hn2 = (__half*)p;                 p += (size_t)N_NODES * HID * 2;
  float* norms2 = (float*)p;                p += (size_t)N_NODES * 4;
  unsigned int* soffs = (unsigned int*)p;   p += (size_t)N_NODES * 4;
  unsigned short* ecnt = (unsigned short*)p; p += (size_t)N_NODES * 2 + 64;
  int* gcur = (int*)p;                      p += (size_t)NB * 4 + 32;
  unsigned int* csr = (unsigned int*)p;     p += ((size_t)NB * CAPB + 16) * 4;
  unsigned int* slots = (unsigned int*)p;   // NB*CAPB u32

  k_gemm_norm<<<GBLK, 256, 0, stream>>>(x, W1, b1, hn1, norms1, gcur);
  k_part<<<NCH, 256, 0, stream>>>(ei, gcur, slots);
  k_csr<<<NB, 256, 0, stream>>>(slots, gcur, csr, soffs, ecnt);

  const int nblW = (N_NODES + 3) / 4;  // wave per node, 4 waves/block
  k_pull1<<<nblW, 256, 0, stream>>>(hn1, norms1, soffs, ecnt, csr, hn2, norms2);
  k_pull2<<<nblW, 256, 0, stream>>>(hn2, norms2, soffs, ecnt, csr, beta, W2, b2, out);
}

// Round 12
// 223.295 us; speedup vs baseline: 1.2875x; 1.1642x over previous
//
#include <hip/hip_runtime.h>
#include <hip/hip_fp16.h>
#include <math.h>

#define N_NODES 100000
#define N_EDGES 3200000
#define EPRIME  (N_EDGES + N_NODES)
#define NFEAT   512
#define HID     16
#define NCLS    10

#define NPB     256                            // nodes per bucket
#define NB      ((N_NODES + NPB - 1) / NPB)    // 391 buckets
#define CHUNK   4096                           // edges per partition chunk
#define NCH     ((EPRIME + CHUNK - 1) / CHUNK) // 806 chunks
#define CAPB    10240                          // fixed region per bucket (mean 8448 + ~19 sigma)
#define NWAVE_G 6250                           // gemm waves: one per 16 rows (6250*16 = 100000)
#define GBLK    ((NWAVE_G + 3) / 4)            // 1563 blocks

typedef _Float16 f16x8 __attribute__((ext_vector_type(8)));
typedef float f32x4 __attribute__((ext_vector_type(4)));

union U2 { unsigned int u; __half2 h; };
__device__ __forceinline__ float2 u2f(unsigned int v) {
  U2 t; t.u = v; return __half22float2(t.h);
}

// ---------------------------------------------------------------------------
// D1: hn1 = fp16(normalize(relu(x @ W1 + b1))); norms1 = ||relu||.
// MFMA v_mfma_f32_16x16x32_f16: one wave per 16 rows, 16 K-steps.
// Replaces the scalar-FMA + 25-shuffles/row version: the shuffle reduce
// (ds_swizzle) serialized on the per-CU DS pipe (~30us/CU at 390 rows/CU);
// MFMA's C/D layout (col=lane&15, row=4*(lane>>4)+reg) needs only 16
// shuffles per 16 rows for the norm.  A-frag: A[row=l&15][k=8*(l>>4)+j];
// B-frag: B[k=8*(l>>4)+j][col=l&15] (W1, pre-converted to f16, 64 VGPR).
// f16 inputs (not bf16): x,W1 magnitudes ~1 -> rel err ~2^-11, fp32 accum.
// Block 0 zeroes gcur for the next dispatch.
// ---------------------------------------------------------------------------
__global__ __launch_bounds__(256) void k_gemm_norm(const float* __restrict__ x,
                                                   const float* __restrict__ W1,
                                                   const float* __restrict__ b1,
                                                   __half* __restrict__ hn1,
                                                   float* __restrict__ norms1,
                                                   int* __restrict__ gcur) {
  if (blockIdx.x == 0)
    for (int i = threadIdx.x; i < NB; i += 256) gcur[i] = 0;

  const int w = blockIdx.x * 4 + (threadIdx.x >> 6);
  if (w >= NWAVE_G) return;
  const int lane = threadIdx.x & 63;
  const int col  = lane & 15;   // A-row / B-col / D-col index
  const int g    = lane >> 4;   // k-group (0..3)
  const int r0   = w * 16;

  // B fragments: bf[t][j] = W1[(t*32 + g*8 + j)*16 + col], one-time load
  // (W1 is 32KB -> L1/L2-resident; cost amortized over 16 rows).
  f16x8 bf[16];
#pragma unroll
  for (int t = 0; t < 16; ++t)
#pragma unroll
    for (int j = 0; j < 8; ++j)
      bf[t][j] = (_Float16)W1[(t * 32 + g * 8 + j) * 16 + col];

  // A stream: lane reads x[r0+col][t*32 + g*8 .. +8) per K-step.
  const float* xr = x + (size_t)(r0 + col) * NFEAT + g * 8;

  f32x4 acc = {0.f, 0.f, 0.f, 0.f};
  float4 a0 = *reinterpret_cast<const float4*>(xr);
  float4 a1 = *reinterpret_cast<const float4*>(xr + 4);

#pragma unroll
  for (int t = 0; t < 16; ++t) {
    float4 n0, n1;
    if (t < 15) {
      n0 = *reinterpret_cast<const float4*>(xr + (t + 1) * 32);
      n1 = *reinterpret_cast<const float4*>(xr + (t + 1) * 32 + 4);
    }
    f16x8 af;
    af[0] = (_Float16)a0.x; af[1] = (_Float16)a0.y;
    af[2] = (_Float16)a0.z; af[3] = (_Float16)a0.w;
    af[4] = (_Float16)a1.x; af[5] = (_Float16)a1.y;
    af[6] = (_Float16)a1.z; af[7] = (_Float16)a1.w;
    acc = __builtin_amdgcn_mfma_f32_16x16x32_f16(af, bf[t], acc, 0, 0, 0);
    if (t < 15) { a0 = n0; a1 = n1; }
  }

  // Epilogue: D[row=4g+c][col] in acc[c].  bias/relu, row-norm via 4-stage
  // butterfly within each 16-lane group (1 DS-op per row vs old 25).
  const float bias = b1[col];
  float v[4], ss[4];
#pragma unroll
  for (int c = 0; c < 4; ++c) {
    v[c] = fmaxf(acc[c] + bias, 0.f);
    ss[c] = v[c] * v[c];
  }
#pragma unroll
  for (int c = 0; c < 4; ++c) {
    ss[c] += __shfl_xor(ss[c], 1);
    ss[c] += __shfl_xor(ss[c], 2);
    ss[c] += __shfl_xor(ss[c], 4);
    ss[c] += __shfl_xor(ss[c], 8);
  }
#pragma unroll
  for (int c = 0; c < 4; ++c) {
    const int r = r0 + g * 4 + c;
    const float nrm = sqrtf(ss[c]);
    const float inv = 1.0f / fmaxf(nrm, 1e-12f);
    hn1[(size_t)r * HID + col] = __float2half_rn(v[c] * inv);
    if (col == c) norms1[r] = nrm;
  }
}

// ---------------------------------------------------------------------------
// D2: partition edges into per-bucket slot regions of packed u32
// (src | local_dst<<20).  One 4096-edge chunk per block; LDS histogram
// gives per-edge rank; one global atomic per touched bucket reserves a
// contiguous run in slots[b*CAPB ...].
// ---------------------------------------------------------------------------
__global__ __launch_bounds__(256) void k_part(const int* __restrict__ ei,
                                              int* __restrict__ gcur,
                                              unsigned int* __restrict__ slots) {
  __shared__ int sh_hist[NB];
  __shared__ int sh_gbase[NB];
  const int tid = threadIdx.x;

  for (int i = tid; i < NB; i += 256) sh_hist[i] = 0;
  __syncthreads();

  const int base = blockIdx.x * CHUNK;
  unsigned int pk[16];
  int bk[16], rk[16];
#pragma unroll
  for (int j = 0; j < 16; ++j) {
    int e = base + j * 256 + tid;
    bool valid = (e < EPRIME);
    int srcv = 0, d = 0;
    if (valid) {
      if (e < N_EDGES) { srcv = ei[e]; d = ei[N_EDGES + e]; }
      else             { srcv = d = e - N_EDGES; }
    }
    bk[j] = valid ? (d >> 8) : -1;
    pk[j] = (unsigned)srcv | ((unsigned)(d & 255) << 20);
    rk[j] = valid ? atomicAdd(&sh_hist[d >> 8], 1) : 0;
  }
  __syncthreads();

  for (int i = tid; i < NB; i += 256) {
    int hc = sh_hist[i];
    sh_gbase[i] = hc ? atomicAdd(&gcur[i], hc) : 0;
  }
  __syncthreads();

#pragma unroll
  for (int j = 0; j < 16; ++j)
    if (bk[j] >= 0)
      slots[(size_t)bk[j] * CAPB + sh_gbase[bk[j]] + rk[j]] = pk[j];
}

// ---------------------------------------------------------------------------
// D3: per-bucket CSR finalize.  Coalesced strided reads of the slot
// region, LDS histogram -> scan -> direct scatter into the fixed csr
// region [b*CAPB, b*CAPB+ne) (L2-local).  Writes soffs/ecnt; zeroes the
// 16-entry over-read pad past ne.
// ---------------------------------------------------------------------------
__global__ __launch_bounds__(256) void k_csr(const unsigned int* __restrict__ slots,
                                             const int* __restrict__ gcur,
                                             unsigned int* __restrict__ csr,
                                             unsigned int* __restrict__ soffs,
                                             unsigned short* __restrict__ ecnt) {
  __shared__ int sh_cnt[NPB];
  __shared__ int sh_cnt2[NPB];
  __shared__ int sh_sc[NPB];
  __shared__ int sh_loffs[NPB];
  const int b = blockIdx.x, tid = threadIdx.x;
  const int ne = gcur[b];
  const unsigned int* my = slots + (size_t)b * CAPB;

  sh_cnt[tid] = 0;
  sh_cnt2[tid] = 0;
  __syncthreads();

  for (int i = tid; i < ne; i += 256) atomicAdd(&sh_cnt[my[i] >> 20], 1);
  __syncthreads();

  const int v = sh_cnt[tid];
  sh_sc[tid] = v;
  __syncthreads();
  for (int d = 1; d < NPB; d <<= 1) {
    int u = (tid >= d) ? sh_sc[tid - d] : 0;
    __syncthreads();
    sh_sc[tid] += u;
    __syncthreads();
  }
  const int excl = sh_sc[tid] - v;
  sh_loffs[tid] = excl;

  if (tid < 16) csr[(size_t)b * CAPB + ne + tid] = 0;  // over-read pad

  const int node = b * NPB + tid;
  if (node < N_NODES) {
    soffs[node] = (unsigned)(b * CAPB + excl);
    ecnt[node]  = (unsigned short)v;
  }
  __syncthreads();

  for (int i = tid; i < ne; i += 256) {
    const unsigned pv = my[i];
    const int local = pv >> 20;
    const int rr = atomicAdd(&sh_cnt2[local], 1);
    csr[(size_t)b * CAPB + sh_loffs[local] + rr] = pv & 0xFFFFF;
  }
}

// ---------------------------------------------------------------------------
// Pull-mode AGNN conv, one wave per dst node.  16 edge slots x 4 feature
// lanes; hn fp16 (L2-resident), fp32 accumulate.  FINAL=false: fuse next
// layer's normalize.  FINAL=true: fuse logits + log_softmax.
// Over-read past e (up to 15 slots) reads the zeroed pad -> src=0, t=0.
// ---------------------------------------------------------------------------
template <bool FINAL>
__device__ __forceinline__ void pull_body(const __half* __restrict__ hn,
                                          const float* __restrict__ norms,
                                          const unsigned int* __restrict__ soffs,
                                          const unsigned short* __restrict__ ecnt,
                                          const unsigned int* __restrict__ csr,
                                          float beta,
                                          __half* __restrict__ out_hn,
                                          float* __restrict__ out_norms,
                                          const float* __restrict__ W2,
                                          const float* __restrict__ b2,
                                          float* __restrict__ out) {
  const int node = blockIdx.x * 4 + (threadIdx.x >> 6);
  if (node >= N_NODES) return;
  const int lane = threadIdx.x & 63;
  const int q    = lane & 3;   // feature quad
  const int slot = lane >> 2;  // edge slot 0..15

  float w4x = 0.f, w4y = 0.f, w4z = 0.f, w4w = 0.f, b2v = 0.f;
  if (FINAL) {
    const int sc = (slot < NCLS) ? slot : 0;
    w4x = W2[(q * 4 + 0) * NCLS + sc];
    w4y = W2[(q * 4 + 1) * NCLS + sc];
    w4z = W2[(q * 4 + 2) * NCLS + sc];
    w4w = W2[(q * 4 + 3) * NCLS + sc];
    b2v = b2[sc];
  }

  const uint2 qraw = *reinterpret_cast<const uint2*>(hn + (size_t)node * HID + q * 4);
  const float2 qa = u2f(qraw.x), qb = u2f(qraw.y);
  const unsigned s = soffs[node];
  const unsigned e = s + ecnt[node];

  float den = 0.f;
  float ax = 0.f, ay = 0.f, az = 0.f, aw = 0.f;

  for (unsigned bi = s; bi < e; bi += 16) {
    const unsigned i = bi + slot;
    const int src = (int)csr[i];  // past-e reads hit the zero pad
    const uint2 rr = *reinterpret_cast<const uint2*>(hn + (size_t)src * HID + q * 4);
    const float2 f0 = u2f(rr.x), f1 = u2f(rr.y);
    float pd = qa.x * f0.x + qa.y * f0.y + qb.x * f1.x + qb.y * f1.y;
    pd += __shfl_xor(pd, 1);
    pd += __shfl_xor(pd, 2);
    const float t = (i < e) ? __expf(beta * pd) : 0.f;
    den += t;
    const float wgt = t * norms[src];
    ax += wgt * f0.x; ay += wgt * f0.y; az += wgt * f1.x; aw += wgt * f1.y;
  }

#pragma unroll
  for (int m = 4; m <= 32; m <<= 1) {
    den += __shfl_xor(den, m);
    ax  += __shfl_xor(ax, m);
    ay  += __shfl_xor(ay, m);
    az  += __shfl_xor(az, m);
    aw  += __shfl_xor(aw, m);
  }
  const float inv = 1.0f / den;  // self-loop guarantees den > 0
  ax *= inv; ay *= inv; az *= inv; aw *= inv;

  if (!FINAL) {
    float ssn = ax * ax + ay * ay + az * az + aw * aw;
    ssn += __shfl_xor(ssn, 1);
    ssn += __shfl_xor(ssn, 2);
    const float nrm = sqrtf(ssn);
    const float ninv = 1.0f / fmaxf(nrm, 1e-12f);
    if (lane < 4) {
      U2 lo, hi;
      lo.h = __floats2half2_rn(ax * ninv, ay * ninv);
      hi.h = __floats2half2_rn(az * ninv, aw * ninv);
      *reinterpret_cast<uint2*>(out_hn + (size_t)node * HID + q * 4) =
          make_uint2(lo.u, hi.u);
      if (lane == 0) out_norms[node] = nrm;
    }
  } else {
    float part = ax * w4x + ay * w4y + az * w4z + aw * w4w;
    part += __shfl_xor(part, 1);
    part += __shfl_xor(part, 2);
    const float logit = part + b2v;  // valid on slots 0..9 (all q replicate)

    float lg[NCLS];
#pragma unroll
    for (int c = 0; c < NCLS; ++c) lg[c] = __shfl(logit, c * 4);
    float m = lg[0];
#pragma unroll
    for (int c = 1; c < NCLS; ++c) m = fmaxf(m, lg[c]);
    float se = 0.f;
#pragma unroll
    for (int c = 0; c < NCLS; ++c) se += __expf(lg[c] - m);
    const float ls = m + logf(se);

    const float myv = __shfl(logit, lane * 4);
    if (lane < NCLS) out[(size_t)node * NCLS + lane] = myv - ls;
  }
}

__global__ __launch_bounds__(256) void k_pull1(const __half* __restrict__ hn1,
                                               const float* __restrict__ norms1,
                                               const unsigned int* __restrict__ soffs,
                                               const unsigned short* __restrict__ ecnt,
                                               const unsigned int* __restrict__ csr,
                                               __half* __restrict__ hn2,
                                               float* __restrict__ norms2) {
  pull_body<false>(hn1, norms1, soffs, ecnt, csr, 1.0f, hn2, norms2,
                   nullptr, nullptr, nullptr);
}

__global__ __launch_bounds__(256) void k_pull2(const __half* __restrict__ hn2,
                                               const float* __restrict__ norms2,
                                               const unsigned int* __restrict__ soffs,
                                               const unsigned short* __restrict__ ecnt,
                                               const unsigned int* __restrict__ csr,
                                               const float* __restrict__ beta_ptr,
                                               const float* __restrict__ W2,
                                               const float* __restrict__ b2,
                                               float* __restrict__ out) {
  pull_body<true>(hn2, norms2, soffs, ecnt, csr, beta_ptr[0], nullptr, nullptr,
                  W2, b2, out);
}

// ---------------------------------------------------------------------------
extern "C" void kernel_launch(void* const* d_in, const int* in_sizes, int n_in,
                              void* d_out, int out_size, void* d_ws, size_t ws_size,
                              hipStream_t stream) {
  const float* x    = (const float*)d_in[0];
  const int*   ei   = (const int*)d_in[1];
  const float* W1   = (const float*)d_in[2];
  const float* b1   = (const float*)d_in[3];
  const float* beta = (const float*)d_in[4];
  const float* W2   = (const float*)d_in[5];
  const float* b2   = (const float*)d_in[6];
  float* out = (float*)d_out;

  // Workspace layout (~39 MB); every array 16B-aligned by construction.
  char* p = (char*)d_ws;
  __half* hn1 = (__half*)p;                 p += (size_t)N_NODES * HID * 2;
  float* norms1 = (float*)p;                p += (size_t)N_NODES * 4;
  __half* hn2 = (__half*)p;                 p += (size_t)N_NODES * HID * 2;
  float* norms2 = (float*)p;                p += (size_t)N_NODES * 4;
  unsigned int* soffs = (unsigned int*)p;   p += (size_t)N_NODES * 4;
  unsigned short* ecnt = (unsigned short*)p; p += (size_t)N_NODES * 2 + 64;
  int* gcur = (int*)p;                      p += (size_t)NB * 4 + 32;
  unsigned int* csr = (unsigned int*)p;     p += ((size_t)NB * CAPB + 16) * 4;
  unsigned int* slots = (unsigned int*)p;   // NB*CAPB u32

  k_gemm_norm<<<GBLK, 256, 0, stream>>>(x, W1, b1, hn1, norms1, gcur);
  k_part<<<NCH, 256, 0, stream>>>(ei, gcur, slots);
  k_csr<<<NB, 256, 0, stream>>>(slots, gcur, csr, soffs, ecnt);

  const int nblW = (N_NODES + 3) / 4;  // wave per node, 4 waves/block
  k_pull1<<<nblW, 256, 0, stream>>>(hn1, norms1, soffs, ecnt, csr, hn2, norms2);
  k_pull2<<<nblW, 256, 0, stream>>>(hn2, norms2, soffs, ecnt, csr, beta, W2, b2, out);
}

// Round 14
// 221.745 us; speedup vs baseline: 1.2965x; 1.0070x over previous
//
#include <hip/hip_runtime.h>
#include <hip/hip_fp16.h>
#include <math.h>

#define N_NODES 100000
#define N_EDGES 3200000
#define EPRIME  (N_EDGES + N_NODES)
#define NFEAT   512
#define HID     16
#define NCLS    10

#define NPB     256                            // nodes per bucket
#define NB      ((N_NODES + NPB - 1) / NPB)    // 391 buckets
#define CHUNK   4096                           // edges per partition chunk
#define NCH     ((EPRIME + CHUNK - 1) / CHUNK) // 806 chunks
#define CAPB    10240                          // fixed region per bucket (mean 8448 + ~19 sigma)
#define NWAVE_G 6250                           // gemm waves: one per 16 rows
#define GBLK    ((NWAVE_G + 3) / 4)            // 1563 blocks

typedef _Float16 f16x8 __attribute__((ext_vector_type(8)));
typedef float f32x4 __attribute__((ext_vector_type(4)));

union U2 { unsigned int u; __half2 h; };
__device__ __forceinline__ float2 u2f(unsigned int v) {
  U2 t; t.u = v; return __half22float2(t.h);
}

// ---------------------------------------------------------------------------
// D1: hn1 = fp16(normalize(relu(x @ W1 + b1))); norms1 = ||relu||.
// MFMA 16x16x32_f16, one wave per 16 rows, 16 K-steps.  2-deep A-prefetch
// (3 rotating row-buffers -> 64B/lane in flight).  C/D layout:
// col=lane&15, row=4*(lane>>4)+c.  Block 0 zeroes gcur for next dispatch.
// ---------------------------------------------------------------------------
__global__ __launch_bounds__(256) void k_gemm_norm(const float* __restrict__ x,
                                                   const float* __restrict__ W1,
                                                   const float* __restrict__ b1,
                                                   __half* __restrict__ hn1,
                                                   float* __restrict__ norms1,
                                                   int* __restrict__ gcur) {
  if (blockIdx.x == 0)
    for (int i = threadIdx.x; i < NB; i += 256) gcur[i] = 0;

  const int w = blockIdx.x * 4 + (threadIdx.x >> 6);
  if (w >= NWAVE_G) return;
  const int lane = threadIdx.x & 63;
  const int col  = lane & 15;
  const int g    = lane >> 4;
  const int r0   = w * 16;

  f16x8 bf[16];
#pragma unroll
  for (int t = 0; t < 16; ++t)
#pragma unroll
    for (int j = 0; j < 8; ++j)
      bf[t][j] = (_Float16)W1[(t * 32 + g * 8 + j) * 16 + col];

  const float* xr = x + (size_t)(r0 + col) * NFEAT + g * 8;

  f32x4 acc = {0.f, 0.f, 0.f, 0.f};
  float4 a0  = *reinterpret_cast<const float4*>(xr);
  float4 a1  = *reinterpret_cast<const float4*>(xr + 4);
  float4 pb0 = *reinterpret_cast<const float4*>(xr + 32);
  float4 pb1 = *reinterpret_cast<const float4*>(xr + 36);

#pragma unroll
  for (int t = 0; t < 16; ++t) {
    float4 n0, n1;
    if (t < 14) {
      n0 = *reinterpret_cast<const float4*>(xr + (t + 2) * 32);
      n1 = *reinterpret_cast<const float4*>(xr + (t + 2) * 32 + 4);
    }
    f16x8 af;
    af[0] = (_Float16)a0.x; af[1] = (_Float16)a0.y;
    af[2] = (_Float16)a0.z; af[3] = (_Float16)a0.w;
    af[4] = (_Float16)a1.x; af[5] = (_Float16)a1.y;
    af[6] = (_Float16)a1.z; af[7] = (_Float16)a1.w;
    acc = __builtin_amdgcn_mfma_f32_16x16x32_f16(af, bf[t], acc, 0, 0, 0);
    a0 = pb0; a1 = pb1;
    if (t < 14) { pb0 = n0; pb1 = n1; }
  }

  const float bias = b1[col];
  float v[4], ss[4];
#pragma unroll
  for (int c = 0; c < 4; ++c) {
    v[c] = fmaxf(acc[c] + bias, 0.f);
    ss[c] = v[c] * v[c];
  }
#pragma unroll
  for (int c = 0; c < 4; ++c) {
    ss[c] += __shfl_xor(ss[c], 1);
    ss[c] += __shfl_xor(ss[c], 2);
    ss[c] += __shfl_xor(ss[c], 4);
    ss[c] += __shfl_xor(ss[c], 8);
  }
#pragma unroll
  for (int c = 0; c < 4; ++c) {
    const int r = r0 + g * 4 + c;
    const float nrm = sqrtf(ss[c]);
    const float inv = 1.0f / fmaxf(nrm, 1e-12f);
    hn1[(size_t)r * HID + col] = __float2half_rn(v[c] * inv);
    if (col == c) norms1[r] = nrm;
  }
}

// ---------------------------------------------------------------------------
// D2: partition edges into per-bucket slot regions of packed u32
// (src | local_dst<<20).  One 4096-edge chunk per block; LDS histogram
// gives per-edge rank; one global atomic per touched bucket reserves a
// contiguous run in slots[b*CAPB ...].
// ---------------------------------------------------------------------------
__global__ __launch_bounds__(256) void k_part(const int* __restrict__ ei,
                                              int* __restrict__ gcur,
                                              unsigned int* __restrict__ slots) {
  __shared__ int sh_hist[NB];
  __shared__ int sh_gbase[NB];
  const int tid = threadIdx.x;

  for (int i = tid; i < NB; i += 256) sh_hist[i] = 0;
  __syncthreads();

  const int base = blockIdx.x * CHUNK;
  unsigned int pk[16];
  int bk[16], rk[16];
#pragma unroll
  for (int j = 0; j < 16; ++j) {
    int e = base + j * 256 + tid;
    bool valid = (e < EPRIME);
    int srcv = 0, d = 0;
    if (valid) {
      if (e < N_EDGES) { srcv = ei[e]; d = ei[N_EDGES + e]; }
      else             { srcv = d = e - N_EDGES; }
    }
    bk[j] = valid ? (d >> 8) : -1;
    pk[j] = (unsigned)srcv | ((unsigned)(d & 255) << 20);
    rk[j] = valid ? atomicAdd(&sh_hist[d >> 8], 1) : 0;
  }
  __syncthreads();

  for (int i = tid; i < NB; i += 256) {
    int hc = sh_hist[i];
    sh_gbase[i] = hc ? atomicAdd(&gcur[i], hc) : 0;
  }
  __syncthreads();

#pragma unroll
  for (int j = 0; j < 16; ++j)
    if (bk[j] >= 0)
      slots[(size_t)bk[j] * CAPB + sh_gbase[bk[j]] + rk[j]] = pk[j];
}

// ---------------------------------------------------------------------------
// D3: per-bucket CSR finalize.  Coalesced strided reads of the slot region,
// LDS histogram -> scan -> direct scatter into fixed csr region
// [b*CAPB, b*CAPB+ne) (L2-local).  Zeroes a 32-entry over-read pad past ne
// (pull prefetches up to e+30).
// ---------------------------------------------------------------------------
__global__ __launch_bounds__(256) void k_csr(const unsigned int* __restrict__ slots,
                                             const int* __restrict__ gcur,
                                             unsigned int* __restrict__ csr,
                                             unsigned int* __restrict__ soffs,
                                             unsigned short* __restrict__ ecnt) {
  __shared__ int sh_cnt[NPB];
  __shared__ int sh_cnt2[NPB];
  __shared__ int sh_sc[NPB];
  __shared__ int sh_loffs[NPB];
  const int b = blockIdx.x, tid = threadIdx.x;
  const int ne = gcur[b];
  const unsigned int* my = slots + (size_t)b * CAPB;

  sh_cnt[tid] = 0;
  sh_cnt2[tid] = 0;
  __syncthreads();

  for (int i = tid; i < ne; i += 256) atomicAdd(&sh_cnt[my[i] >> 20], 1);
  __syncthreads();

  const int v = sh_cnt[tid];
  sh_sc[tid] = v;
  __syncthreads();
  for (int d = 1; d < NPB; d <<= 1) {
    int u = (tid >= d) ? sh_sc[tid - d] : 0;
    __syncthreads();
    sh_sc[tid] += u;
    __syncthreads();
  }
  const int excl = sh_sc[tid] - v;
  sh_loffs[tid] = excl;

  if (tid < 32) csr[(size_t)b * CAPB + ne + tid] = 0;  // over-read pad (e+30 max)

  const int node = b * NPB + tid;
  if (node < N_NODES) {
    soffs[node] = (unsigned)(b * CAPB + excl);
    ecnt[node]  = (unsigned short)v;
  }
  __syncthreads();

  for (int i = tid; i < ne; i += 256) {
    const unsigned pv = my[i];
    const int local = pv >> 20;
    const int rr = atomicAdd(&sh_cnt2[local], 1);
    csr[(size_t)b * CAPB + sh_loffs[local] + rr] = pv & 0xFFFFF;
  }
}

// ---------------------------------------------------------------------------
// Pull-mode AGNN conv, one wave per dst node, 16 edge slots x 4 feature
// lanes, SOFTWARE-PIPELINED: next iteration's csr load AND hn gather are
// issued before processing the current one.  hn fp16 (L2-resident), fp32
// accumulate.  FINAL=false: fuse next normalize; FINAL=true: fuse logits +
// log_softmax.  Prefetch reads up to e+30 -> 32-entry zero pad.
// ---------------------------------------------------------------------------
template <bool FINAL>
__device__ __forceinline__ void pull_body(const __half* __restrict__ hn,
                                          const float* __restrict__ norms,
                                          const unsigned int* __restrict__ soffs,
                                          const unsigned short* __restrict__ ecnt,
                                          const unsigned int* __restrict__ csr,
                                          float beta,
                                          __half* __restrict__ out_hn,
                                          float* __restrict__ out_norms,
                                          const float* __restrict__ W2,
                                          const float* __restrict__ b2,
                                          float* __restrict__ out) {
  const int node = blockIdx.x * 4 + (threadIdx.x >> 6);
  if (node >= N_NODES) return;
  const int lane = threadIdx.x & 63;
  const int q    = lane & 3;
  const int slot = lane >> 2;

  float w4x = 0.f, w4y = 0.f, w4z = 0.f, w4w = 0.f, b2v = 0.f;
  if (FINAL) {
    const int sc = (slot < NCLS) ? slot : 0;
    w4x = W2[(q * 4 + 0) * NCLS + sc];
    w4y = W2[(q * 4 + 1) * NCLS + sc];
    w4z = W2[(q * 4 + 2) * NCLS + sc];
    w4w = W2[(q * 4 + 3) * NCLS + sc];
    b2v = b2[sc];
  }

  const uint2 qraw = *reinterpret_cast<const uint2*>(hn + (size_t)node * HID + q * 4);
  const float2 qa = u2f(qraw.x), qb = u2f(qraw.y);
  const unsigned s = soffs[node];
  const unsigned e = s + ecnt[node];

  float den = 0.f;
  float ax = 0.f, ay = 0.f, az = 0.f, aw = 0.f;

  // pipeline prologue: csr + gather for iteration 0
  int src0 = (int)csr[s + slot];
  uint2 r0 = *reinterpret_cast<const uint2*>(hn + (size_t)src0 * HID + q * 4);

  for (unsigned bi = s; bi < e; bi += 16) {
    const int srcN = (int)csr[bi + 16 + slot];  // pad-safe to e+30
    const uint2 rN = *reinterpret_cast<const uint2*>(hn + (size_t)srcN * HID + q * 4);

    const unsigned i = bi + slot;
    const float2 f0 = u2f(r0.x), f1 = u2f(r0.y);
    float pd = qa.x * f0.x + qa.y * f0.y + qb.x * f1.x + qb.y * f1.y;
    pd += __shfl_xor(pd, 1);
    pd += __shfl_xor(pd, 2);
    const float t = (i < e) ? __expf(beta * pd) : 0.f;
    den += t;
    const float wgt = t * norms[src0];
    ax += wgt * f0.x; ay += wgt * f0.y; az += wgt * f1.x; aw += wgt * f1.y;

    src0 = srcN; r0 = rN;
  }

#pragma unroll
  for (int m = 4; m <= 32; m <<= 1) {
    den += __shfl_xor(den, m);
    ax  += __shfl_xor(ax, m);
    ay  += __shfl_xor(ay, m);
    az  += __shfl_xor(az, m);
    aw  += __shfl_xor(aw, m);
  }
  const float inv = 1.0f / den;  // self-loop guarantees den > 0
  ax *= inv; ay *= inv; az *= inv; aw *= inv;

  if (!FINAL) {
    float ssn = ax * ax + ay * ay + az * az + aw * aw;
    ssn += __shfl_xor(ssn, 1);
    ssn += __shfl_xor(ssn, 2);
    const float nrm = sqrtf(ssn);
    const float ninv = 1.0f / fmaxf(nrm, 1e-12f);
    if (lane < 4) {
      U2 lo, hi;
      lo.h = __floats2half2_rn(ax * ninv, ay * ninv);
      hi.h = __floats2half2_rn(az * ninv, aw * ninv);
      *reinterpret_cast<uint2*>(out_hn + (size_t)node * HID + q * 4) =
          make_uint2(lo.u, hi.u);
      if (lane == 0) out_norms[node] = nrm;
    }
  } else {
    float part = ax * w4x + ay * w4y + az * w4z + aw * w4w;
    part += __shfl_xor(part, 1);
    part += __shfl_xor(part, 2);
    const float logit = part + b2v;

    float lg[NCLS];
#pragma unroll
    for (int c = 0; c < NCLS; ++c) lg[c] = __shfl(logit, c * 4);
    float m = lg[0];
#pragma unroll
    for (int c = 1; c < NCLS; ++c) m = fmaxf(m, lg[c]);
    float se = 0.f;
#pragma unroll
    for (int c = 0; c < NCLS; ++c) se += __expf(lg[c] - m);
    const float ls = m + logf(se);

    const float myv = __shfl(logit, lane * 4);
    if (lane < NCLS) out[(size_t)node * NCLS + lane] = myv - ls;
  }
}

__global__ __launch_bounds__(256) void k_pull1(const __half* __restrict__ hn1,
                                               const float* __restrict__ norms1,
                                               const unsigned int* __restrict__ soffs,
                                               const unsigned short* __restrict__ ecnt,
                                               const unsigned int* __restrict__ csr,
                                               __half* __restrict__ hn2,
                                               float* __restrict__ norms2) {
  pull_body<false>(hn1, norms1, soffs, ecnt, csr, 1.0f, hn2, norms2,
                   nullptr, nullptr, nullptr);
}

__global__ __launch_bounds__(256) void k_pull2(const __half* __restrict__ hn2,
                                               const float* __restrict__ norms2,
                                               const unsigned int* __restrict__ soffs,
                                               const unsigned short* __restrict__ ecnt,
                                               const unsigned int* __restrict__ csr,
                                               const float* __restrict__ beta_ptr,
                                               const float* __restrict__ W2,
                                               const float* __restrict__ b2,
                                               float* __restrict__ out) {
  pull_body<true>(hn2, norms2, soffs, ecnt, csr, beta_ptr[0], nullptr, nullptr,
                  W2, b2, out);
}

// ---------------------------------------------------------------------------
extern "C" void kernel_launch(void* const* d_in, const int* in_sizes, int n_in,
                              void* d_out, int out_size, void* d_ws, size_t ws_size,
                              hipStream_t stream) {
  const float* x    = (const float*)d_in[0];
  const int*   ei   = (const int*)d_in[1];
  const float* W1   = (const float*)d_in[2];
  const float* b1   = (const float*)d_in[3];
  const float* beta = (const float*)d_in[4];
  const float* W2   = (const float*)d_in[5];
  const float* b2   = (const float*)d_in[6];
  float* out = (float*)d_out;

  // Workspace layout (~39 MB); every array 16B-aligned by construction.
  char* p = (char*)d_ws;
  __half* hn1 = (__half*)p;                 p += (size_t)N_NODES * HID * 2;
  float* norms1 = (float*)p;                p += (size_t)N_NODES * 4;
  __half* hn2 = (__half*)p;                 p += (size_t)N_NODES * HID * 2;
  float* norms2 = (float*)p;                p += (size_t)N_NODES * 4;
  unsigned int* soffs = (unsigned int*)p;   p += (size_t)N_NODES * 4;
  unsigned short* ecnt = (unsigned short*)p; p += (size_t)N_NODES * 2 + 64;
  int* gcur = (int*)p;                      p += (size_t)NB * 4 + 32;
  unsigned int* csr = (unsigned int*)p;     p += ((size_t)NB * CAPB + 32) * 4;
  unsigned int* slots = (unsigned int*)p;   // NB*CAPB u32

  k_gemm_norm<<<GBLK, 256, 0, stream>>>(x, W1, b1, hn1, norms1, gcur);
  k_part<<<NCH, 256, 0, stream>>>(ei, gcur, slots);
  k_csr<<<NB, 256, 0, stream>>>(slots, gcur, csr, soffs, ecnt);

  const int nblW = (N_NODES + 3) / 4;  // wave per node, 4 waves/block
  k_pull1<<<nblW, 256, 0, stream>>>(hn1, norms1, soffs, ecnt, csr, hn2, norms2);
  k_pull2<<<nblW, 256, 0, stream>>>(hn2, norms2, soffs, ecnt, csr, beta, W2, b2, out);
}